// Round 17
// baseline (191.843 us; speedup 1.0000x reference)
//
#include <hip/hip_runtime.h>
#include <hip/hip_bf16.h>

#define CCH 256
#define CQK 32
#define NHW 4096

typedef float f32x4 __attribute__((ext_vector_type(4)));
typedef _Float16 hv8 __attribute__((ext_vector_type(8)));
typedef _Float16 hv4 __attribute__((ext_vector_type(4)));
typedef __fp16 fv2 __attribute__((ext_vector_type(2)));   // cvt_pkrtz native type

// Direct global->LDS DMA, 16 B/lane. LDS dest = wave-uniform base + lane*16.
typedef __attribute__((address_space(3))) unsigned int lds_u32_t;
typedef __attribute__((address_space(1))) const unsigned int glb_u32_t;
__device__ __forceinline__ void gll16(const _Float16* gp, _Float16* lp) {
    __builtin_amdgcn_global_load_lds((glb_u32_t*)gp, (lds_u32_t*)lp, 16, 0, 0);
}

// ---------------------------------------------------------------------------
// Prep kernel: convert Wall = concat(b_w, c_w, d_w) fp32 -> fp16 [320][256];
// b_w rows prescaled by log2(e) so QK^T comes out in exp2 units. Grid 80 x 256.
// ---------------------------------------------------------------------------
__global__ __launch_bounds__(256) void prep_kernel(
    const float* __restrict__ b_w, const float* __restrict__ c_w,
    const float* __restrict__ d_w, _Float16* __restrict__ Wh)
{
    const int bid = blockIdx.x, tid = threadIdx.x;
    const int idx = (bid * 256 + tid) * 4;
    const int row = idx >> 8, col = idx & 255;
    const float* src = (row < 32) ? (b_w + row * CCH + col)
                     : (row < 64) ? (c_w + (row - 32) * CCH + col)
                                  : (d_w + (row - 64) * CCH + col);
    const float scl = (row < 32) ? 1.4426950408889634f : 1.0f;
    float4 v = *reinterpret_cast<const float4*>(src);
    _Float16* dst = Wh + (size_t)row * CCH + col;
    dst[0] = (_Float16)(v.x * scl); dst[1] = (_Float16)(v.y * scl);
    dst[2] = (_Float16)(v.z * scl); dst[3] = (_Float16)(v.w * scl);
}

// ---------------------------------------------------------------------------
// Projection kernel v2 (R10 verified): MFMA loop + LDS-staged coalesced
// epilogue. Unchanged.
// ---------------------------------------------------------------------------
__global__ __launch_bounds__(256) void proj_kernel(
    const float* __restrict__ a, const _Float16* __restrict__ Wh,
    const float* __restrict__ b_b, const float* __restrict__ c_b,
    const float* __restrict__ d_b,
    _Float16* __restrict__ bqT, _Float16* __restrict__ ckT,
    _Float16* __restrict__ dv)
{
    __shared__ _Float16 aT[32][CCH + 24];   // [pos][ch] input transpose
    __shared__ _Float16 oT[256][34];        // dv staging [ch][pos]
    __shared__ _Float16 pqT[32][34];        // bq staging [pos][ch]
    __shared__ _Float16 pkT[32][34];        // ck staging [pos][ch]

    const int n    = blockIdx.x >> 7;
    const int i0   = (blockIdx.x & 127) << 5;
    const int tid  = threadIdx.x;
    const int lane = tid & 63;
    const int wave = tid >> 6;
    const int l15  = lane & 15;
    const int quad = lane >> 4;

    {
        const float* ap = a + (size_t)(n*CCH + tid)*NHW + i0;
        #pragma unroll
        for (int j = 0; j < 8; ++j) {
            float4 v = *reinterpret_cast<const float4*>(ap + j*4);
            aT[j*4+0][tid] = (_Float16)v.x;
            aT[j*4+1][tid] = (_Float16)v.y;
            aT[j*4+2][tid] = (_Float16)v.z;
            aT[j*4+3][tid] = (_Float16)v.w;
        }
    }
    __syncthreads();

    const f32x4 zf = {0.f, 0.f, 0.f, 0.f};
    f32x4 acc[5][2];
    #pragma unroll
    for (int t = 0; t < 5; ++t) { acc[t][0] = zf; acc[t][1] = zf; }

    const int ch0w = wave * 80;

    #pragma unroll
    for (int ks = 0; ks < 8; ++ks) {
        const int k0 = ks * 32;
        hv8 af0 = *reinterpret_cast<const hv8*>(&aT[l15][k0 + quad*8]);
        hv8 af1 = *reinterpret_cast<const hv8*>(&aT[16 + l15][k0 + quad*8]);
        #pragma unroll
        for (int t = 0; t < 5; ++t) {
            const int ch0 = ch0w + t*16;
            hv8 bf = *reinterpret_cast<const hv8*>(
                Wh + (size_t)(ch0 + l15)*CCH + k0 + quad*8);
            acc[t][0] = __builtin_amdgcn_mfma_f32_16x16x32_f16(af0, bf, acc[t][0], 0, 0, 0);
            acc[t][1] = __builtin_amdgcn_mfma_f32_16x16x32_f16(af1, bf, acc[t][1], 0, 0, 0);
        }
    }

    // ---- stage results into LDS (biases applied here)
    const int posq = quad*4;                // local pos base
    #pragma unroll
    for (int t = 0; t < 5; ++t) {
        const int ch0 = ch0w + t*16;
        if (ch0 < 64) {
            const float* bias_arr = (ch0 < 32) ? b_b : c_b;
            const int    ch       = (ch0 & 31) + l15;
            const float  bias     = bias_arr[ch] *
                ((ch0 < 32) ? 1.4426950408889634f : 1.0f);
            #pragma unroll
            for (int nf = 0; nf < 2; ++nf) {
                #pragma unroll
                for (int r = 0; r < 4; ++r) {
                    const int pos = posq + nf*16 + r;
                    if (ch0 < 32) pqT[pos][ch] = (_Float16)(acc[t][nf][r] + bias);
                    else          pkT[pos][ch] = (_Float16)(acc[t][nf][r] + bias);
                }
            }
        } else {
            const int ch   = ch0 - 64 + l15;
            const float bias = d_b[ch];
            #pragma unroll
            for (int nf = 0; nf < 2; ++nf) {
                hv4 v = { (_Float16)(acc[t][nf][0] + bias),
                          (_Float16)(acc[t][nf][1] + bias),
                          (_Float16)(acc[t][nf][2] + bias),
                          (_Float16)(acc[t][nf][3] + bias) };
                *reinterpret_cast<hv4*>(&oT[ch][posq + nf*16]) = v;
            }
        }
    }
    __syncthreads();

    // ---- coalesced global writes
    {
        const int p   = (tid & 127) >> 2;
        const int seg = (tid & 3) << 3;
        if (tid < 128) {
            *reinterpret_cast<int4*>(
                bqT + ((size_t)n*NHW + i0 + p)*CQK + seg) =
                *reinterpret_cast<const int4*>(&pqT[p][seg]);
        } else {
            *reinterpret_cast<int4*>(
                ckT + ((size_t)n*NHW + i0 + p)*CQK + seg) =
                *reinterpret_cast<const int4*>(&pkT[p][seg]);
        }
    }
    #pragma unroll
    for (int pass = 0; pass < 4; ++pass) {
        const int row = pass*64 + (tid >> 2);
        const int seg = (tid & 3) << 3;
        *reinterpret_cast<int4*>(
            dv + ((size_t)(n*CCH + row))*NHW + i0 + seg) =
            *reinterpret_cast<const int4*>(&oT[row][seg]);
    }
}

// ---------------------------------------------------------------------------
// Pass B v16: R15 structure (wave-autonomous, single-buffer V via gll16,
// zero in-loop barriers, T5 setprio -- verified best 74us) with HALVED
// q-tile per wave (32 q, X in {0,1}) to RAISE OCCUPANCY:
//  * grid 512 -> 1024 (4n x 128qt x 2cg), XCD-swizzled
//  * acc 128 -> 64 AGPR; pb & merge buffers halve -> LDS 44,032 B
//  * 3 blocks/CU (12 waves/CU, 3 waves/SIMD) vs R15's 2 blocks/CU --
//    R4/R16 proved TLP is what this latency-bound loop needs.
//  * __launch_bounds__(256,3) caps regs at ~170 (est 95 arch + 72 acc).
// Cost: V-read-per-MFMA doubles (~10us chip-wide LDS) -- covered by 1.5x TLP
// if occupancy materializes. exp total unchanged (cg=2 as R15).
// smem carve (44,032 B): vbuf g*8192 (0..32768) | pb 32768+g*2560 |
// lbuf@43008 | mbuf@43520 | merge (post-loop, aliases vbuf): buf1@0
// [128co][36q] f32 18,432 | buf2@18432.
// ---------------------------------------------------------------------------
__global__ __launch_bounds__(256, 3) void attn_kernel(
    const _Float16* __restrict__ bqT, const _Float16* __restrict__ ckT,
    const _Float16* __restrict__ dv,
    const float* __restrict__ a, const float* __restrict__ alpha_p,
    float* __restrict__ out)
{
    __shared__ __align__(16) char smem[44032];

    // XCD swizzle: 1024 blocks, 8 XCDs -> XCD k owns logical [k*128,(k+1)*128)
    const int bx   = ((blockIdx.x & 7) << 7) | (blockIdx.x >> 3);
    const int n    = bx >> 8;
    const int cg   = (bx >> 7) & 1;
    const int qt   = bx & 127;
    const int q0b  = qt << 5;           // block covers 32 q
    const int co0  = cg << 7;           // 128 output channels
    const int tid  = threadIdx.x;
    const int g    = tid >> 6;          // wave = k-group 0..3
    const int lane = tid & 63;
    const int l15  = lane & 15;
    const int quad = lane >> 4;
    const int kg0  = g << 10;           // keys [g*1024, (g+1)*1024)

    _Float16* vbuf = (_Float16*)(smem + g*8192);          // [128 co][32 k] swizzled
    _Float16* pb   = (_Float16*)(smem + 32768 + g*2560);  // 2 slabs of [16][40]
    float*    lbuf = (float*)(smem + 43008);              // [4 g][32 q]
    float*    mbuf = (float*)(smem + 43520);              // [4 g][32 q]

    const f32x4 zf = {0.f, 0.f, 0.f, 0.f};
    const _Float16 one_h = (_Float16)1.0f;
    const hv8 ones = { one_h, one_h, one_h, one_h, one_h, one_h, one_h, one_h };

    // q fragments, 2 groups of 16 q (covers the block's 32 q)
    hv8 qf[2];
    #pragma unroll
    for (int X = 0; X < 2; ++X) {
        const int q = q0b + X*16 + l15;
        qf[X] = *reinterpret_cast<const hv8*>(
            bqT + ((size_t)n*NHW + q)*CQK + quad*8);
    }

    // kf base for this lane within this group's key range
    const _Float16* ckbase = ckT + ((size_t)(n*NHW + kg0 + l15))*CQK + quad*8;

    // ---- batched per-group row-max prologue: 8 batches x 8 kf (1024 keys)
    float mneg[2];
    {
        float mx[2] = {-1e30f, -1e30f};
        #pragma unroll
        for (int bt = 0; bt < 8; ++bt) {
            hv8 kb[8];
            #pragma unroll
            for (int j = 0; j < 8; ++j)
                kb[j] = *reinterpret_cast<const hv8*>(
                    ckbase + (size_t)(bt*128 + j*16)*CQK);
            #pragma unroll
            for (int X = 0; X < 2; ++X) {
                float bm[8];
                #pragma unroll
                for (int j = 0; j < 8; ++j) {
                    f32x4 s = __builtin_amdgcn_mfma_f32_16x16x32_f16(
                        kb[j], qf[X], zf, 0, 0, 0);
                    bm[j] = fmaxf(fmaxf(s[0], s[1]), fmaxf(s[2], s[3]));
                }
                float m0 = fmaxf(fmaxf(bm[0], bm[1]), fmaxf(bm[2], bm[3]));
                float m1 = fmaxf(fmaxf(bm[4], bm[5]), fmaxf(bm[6], bm[7]));
                mx[X] = fmaxf(mx[X], fmaxf(m0, m1));
            }
        }
        #pragma unroll
        for (int X = 0; X < 2; ++X) {
            mx[X] = fmaxf(mx[X], __shfl_xor(mx[X], 16, 64));
            mx[X] = fmaxf(mx[X], __shfl_xor(mx[X], 32, 64));
            mneg[X] = -mx[X];
        }
    }

    f32x4 acc[2][8];
    #pragma unroll
    for (int X = 0; X < 2; ++X)
        #pragma unroll
        for (int t = 0; t < 8; ++t) acc[X][t] = zf;
    f32x4 accL[2];
    #pragma unroll
    for (int X = 0; X < 2; ++X) accL[X] = zf;

    // ---- staging: 8 x gll16 per wave covers 128 co rows x 32 k.
    const int rl4 = lane >> 2;
    const int sl  = lane & 3;
    const _Float16* dvs = dv
        + (size_t)(n*CCH + co0 + rl4)*NHW + kg0 + 8*(sl ^ ((rl4 >> 1) & 3));

    // swizzled V read col (halves): k-slot quad*8 XOR row-hash
    const int c0h = (quad*8) ^ (((l15 >> 1) & 3) << 3);

    // S^T/exp for one 32-key tile, both q-groups -> pb (fixed minit)
    auto softmax_tile = [&](const hv8* kf) {
        #pragma unroll
        for (int X = 0; X < 2; ++X) {
            const f32x4 minit = {mneg[X], mneg[X], mneg[X], mneg[X]};
            #pragma unroll
            for (int f = 0; f < 2; ++f) {
                f32x4 s = __builtin_amdgcn_mfma_f32_16x16x32_f16(
                    kf[f], qf[X], minit, 0, 0, 0);
                float p0 = __builtin_amdgcn_exp2f(s[0]);
                float p1 = __builtin_amdgcn_exp2f(s[1]);
                float p2 = __builtin_amdgcn_exp2f(s[2]);
                float p3 = __builtin_amdgcn_exp2f(s[3]);
                fv2 lo = __builtin_amdgcn_cvt_pkrtz(p0, p1);
                fv2 hi = __builtin_amdgcn_cvt_pkrtz(p2, p3);
                uint2 w;
                w.x = __builtin_bit_cast(unsigned, lo);
                w.y = __builtin_bit_cast(unsigned, hi);
                *reinterpret_cast<uint2*>(
                    pb + X*640 + l15*40 + f*16 + quad*4) = w;
            }
        }
    };

    hv8 pf0[2];
    auto read_pf = [&]() {
        #pragma unroll
        for (int X = 0; X < 2; ++X)
            pf0[X] = *reinterpret_cast<const hv8*>(pb + X*640 + l15*40 + quad*8);
    };

    auto stage = [&](int kt) {
        #pragma unroll
        for (int j = 0; j < 8; ++j)
            gll16(dvs + (size_t)(j*16)*NHW + kt*32, vbuf + j*512);
    };

    auto load_kf = [&](int key0, hv8* kf) {
        #pragma unroll
        for (int f = 0; f < 2; ++f)
            kf[f] = *reinterpret_cast<const hv8*>(
                ckbase + (size_t)(key0 + f*16)*CQK);
    };

    // ---- prologue: stage V(0), softmax(0) under the DMA, wait, pf(0)
    {
        stage(0);
        hv8 kf0[2];
        load_kf(0, kf0);
        softmax_tile(kf0);
        read_pf();
        asm volatile("s_waitcnt vmcnt(0)" ::: "memory");
        __builtin_amdgcn_sched_barrier(0);
    }

    for (int kt = 0; kt < 32; ++kt) {
        hv8 kfn[2];
        if (kt < 31) load_kf((kt + 1)*32, kfn);

        // ---- PV(kt): each V fragment feeds both q-groups (T5 setprio wrap)
        __builtin_amdgcn_s_setprio(1);
        #pragma unroll
        for (int t = 0; t < 8; ++t) {
            hv8 d0 = *reinterpret_cast<const hv8*>(vbuf + (t*16 + l15)*32 + c0h);
            #pragma unroll
            for (int X = 0; X < 2; ++X)
                acc[X][t] = __builtin_amdgcn_mfma_f32_16x16x32_f16(
                    pf0[X], d0, acc[X][t], 0, 0, 0);
        }
        #pragma unroll
        for (int X = 0; X < 2; ++X)
            accL[X] = __builtin_amdgcn_mfma_f32_16x16x32_f16(pf0[X], ones, accL[X], 0, 0, 0);
        __builtin_amdgcn_s_setprio(0);

        if (kt < 31) {
            // all V(kt) ds_reads retired -> buffer reusable (same wave only)
            asm volatile("s_waitcnt lgkmcnt(0)" ::: "memory");
            __builtin_amdgcn_sched_barrier(0);
            stage(kt + 1);              // DMA issue
            softmax_tile(kfn);          // covers DMA latency (MFMA+exp+pb)
            read_pf();                  // pf(kt+1), same-wave LDS order
            asm volatile("s_waitcnt vmcnt(0)" ::: "memory");   // DMA landed
            __builtin_amdgcn_sched_barrier(0);
        }
    }

    // ---- align k-group partials to common max, merge, epilogue
    if (lane < 16) {
        #pragma unroll
        for (int X = 0; X < 2; ++X)
            mbuf[g*32 + X*16 + l15] = -mneg[X];
    }
    __syncthreads();

    {
        #pragma unroll
        for (int X = 0; X < 2; ++X) {
            const int qloc = X*16 + quad*4;
            float4 m0 = *reinterpret_cast<float4*>(&mbuf[0*32 + qloc]);
            float4 m1 = *reinterpret_cast<float4*>(&mbuf[1*32 + qloc]);
            float4 m2 = *reinterpret_cast<float4*>(&mbuf[2*32 + qloc]);
            float4 m3 = *reinterpret_cast<float4*>(&mbuf[3*32 + qloc]);
            float4 mm;
            mm.x = fmaxf(fmaxf(m0.x, m1.x), fmaxf(m2.x, m3.x));
            mm.y = fmaxf(fmaxf(m0.y, m1.y), fmaxf(m2.y, m3.y));
            mm.z = fmaxf(fmaxf(m0.z, m1.z), fmaxf(m2.z, m3.z));
            mm.w = fmaxf(fmaxf(m0.w, m1.w), fmaxf(m2.w, m3.w));
            float4 mo = (g == 0) ? m0 : (g == 1) ? m1 : (g == 2) ? m2 : m3;
            float sc0 = __builtin_amdgcn_exp2f(mo.x - mm.x);
            float sc1 = __builtin_amdgcn_exp2f(mo.y - mm.y);
            float sc2 = __builtin_amdgcn_exp2f(mo.z - mm.z);
            float sc3 = __builtin_amdgcn_exp2f(mo.w - mm.w);
            #pragma unroll
            for (int t = 0; t < 8; ++t) {
                acc[X][t][0] *= sc0; acc[X][t][1] *= sc1;
                acc[X][t][2] *= sc2; acc[X][t][3] *= sc3;
            }
            accL[X][0] *= sc0; accL[X][1] *= sc1;
            accL[X][2] *= sc2; accL[X][3] *= sc3;
        }
    }
    if (l15 == 0) {
        #pragma unroll
        for (int X = 0; X < 2; ++X)
            *reinterpret_cast<float4*>(&lbuf[g*32 + X*16 + quad*4]) =
                *reinterpret_cast<float4*>(&accL[X]);
    }
    __syncthreads();

    float* buf1 = (float*)smem;                   // [128 co][36 q]
    float* buf2 = (float*)(smem + 18432);

    // Round A: g1 -> buf1, g3 -> buf2
    if (g == 1 || g == 3) {
        float* b = (g == 1) ? buf1 : buf2;
        #pragma unroll
        for (int X = 0; X < 2; ++X)
            #pragma unroll
            for (int t = 0; t < 8; ++t)
                *reinterpret_cast<float4*>(
                    &b[(t*16 + l15)*36 + X*16 + quad*4]) =
                    *reinterpret_cast<float4*>(&acc[X][t]);
    }
    __syncthreads();
    if (g == 0 || g == 2) {
        float* b = (g == 0) ? buf1 : buf2;
        #pragma unroll
        for (int X = 0; X < 2; ++X)
            #pragma unroll
            for (int t = 0; t < 8; ++t) {
                float4 p = *reinterpret_cast<float4*>(
                    &b[(t*16 + l15)*36 + X*16 + quad*4]);
                acc[X][t][0] += p.x; acc[X][t][1] += p.y;
                acc[X][t][2] += p.z; acc[X][t][3] += p.w;
            }
    }
    __syncthreads();
    // Round B: g2 -> buf1
    if (g == 2) {
        #pragma unroll
        for (int X = 0; X < 2; ++X)
            #pragma unroll
            for (int t = 0; t < 8; ++t)
                *reinterpret_cast<float4*>(
                    &buf1[(t*16 + l15)*36 + X*16 + quad*4]) =
                    *reinterpret_cast<float4*>(&acc[X][t]);
    }
    __syncthreads();
    if (g == 0) {
        const float alpha = alpha_p[0];
        #pragma unroll
        for (int X = 0; X < 2; ++X) {
            const int qloc = X*16 + quad*4;
            #pragma unroll
            for (int t = 0; t < 8; ++t) {
                float4 p = *reinterpret_cast<float4*>(
                    &buf1[(t*16 + l15)*36 + qloc]);
                acc[X][t][0] += p.x; acc[X][t][1] += p.y;
                acc[X][t][2] += p.z; acc[X][t][3] += p.w;
            }
            float4 l0 = *reinterpret_cast<float4*>(&lbuf[0*32 + qloc]);
            float4 l1 = *reinterpret_cast<float4*>(&lbuf[1*32 + qloc]);
            float4 l2 = *reinterpret_cast<float4*>(&lbuf[2*32 + qloc]);
            float4 l3 = *reinterpret_cast<float4*>(&lbuf[3*32 + qloc]);
            f32x4 rl;
            rl[0] = alpha / (l0.x + l1.x + l2.x + l3.x);
            rl[1] = alpha / (l0.y + l1.y + l2.y + l3.y);
            rl[2] = alpha / (l0.z + l1.z + l2.z + l3.z);
            rl[3] = alpha / (l0.w + l1.w + l2.w + l3.w);
            #pragma unroll
            for (int t = 0; t < 8; ++t) {
                const size_t off =
                    ((size_t)(n*CCH + co0 + t*16 + l15))*NHW + q0b + qloc;
                float4 av = *reinterpret_cast<const float4*>(a + off);
                float4 o;
                o.x = acc[X][t][0]*rl[0] + av.x;
                o.y = acc[X][t][1]*rl[1] + av.y;
                o.z = acc[X][t][2]*rl[2] + av.z;
                o.w = acc[X][t][3]*rl[3] + av.w;
                *reinterpret_cast<float4*>(out + off) = o;
            }
        }
    }
}

extern "C" void kernel_launch(void* const* d_in, const int* in_sizes, int n_in,
                              void* d_out, int out_size, void* d_ws, size_t ws_size,
                              hipStream_t stream)
{
    const float* a    = (const float*)d_in[0];
    const float* b_w  = (const float*)d_in[1];
    const float* b_b  = (const float*)d_in[2];
    const float* c_w  = (const float*)d_in[3];
    const float* c_b  = (const float*)d_in[4];
    const float* d_w  = (const float*)d_in[5];
    const float* d_b  = (const float*)d_in[6];
    const float* alp  = (const float*)d_in[7];
    float* out = (float*)d_out;

    _Float16* bqT  = (_Float16*)d_ws;                 // [4][4096][32] fp16, 1 MB
    _Float16* ckT  = bqT + (size_t)4*NHW*CQK;         // [4][4096][32] fp16, 1 MB
    _Float16* dv   = ckT + (size_t)4*NHW*CQK;         // [4][256][4096] fp16, 8 MB
    _Float16* Wh   = dv + (size_t)4*CCH*NHW;          // [320][256] fp16, 160 KB

    prep_kernel<<<80, 256, 0, stream>>>(b_w, c_w, d_w, Wh);
    proj_kernel<<<512, 256, 0, stream>>>(a, Wh, b_b, c_b, d_b, bqT, ckT, dv);
    attn_kernel<<<1024, 256, 0, stream>>>(bqT, ckT, dv, a, alp, out);
}

// Round 18
// 158.084 us; speedup vs baseline: 1.2135x; 1.2135x over previous
//
#include <hip/hip_runtime.h>
#include <hip/hip_bf16.h>

#define CCH 256
#define CQK 32
#define NHW 4096

typedef float f32x4 __attribute__((ext_vector_type(4)));
typedef _Float16 hv8 __attribute__((ext_vector_type(8)));
typedef _Float16 hv4 __attribute__((ext_vector_type(4)));
typedef __fp16 fv2 __attribute__((ext_vector_type(2)));   // cvt_pkrtz native type

// Direct global->LDS DMA, 16 B/lane. LDS dest = wave-uniform base + lane*16.
typedef __attribute__((address_space(3))) unsigned int lds_u32_t;
typedef __attribute__((address_space(1))) const unsigned int glb_u32_t;
__device__ __forceinline__ void gll16(const _Float16* gp, _Float16* lp) {
    __builtin_amdgcn_global_load_lds((glb_u32_t*)gp, (lds_u32_t*)lp, 16, 0, 0);
}

// ---------------------------------------------------------------------------
// Prep kernel: convert Wall = concat(b_w, c_w, d_w) fp32 -> fp16 [320][256];
// b_w rows prescaled by log2(e) so QK^T comes out in exp2 units. Grid 80 x 256.
// ---------------------------------------------------------------------------
__global__ __launch_bounds__(256) void prep_kernel(
    const float* __restrict__ b_w, const float* __restrict__ c_w,
    const float* __restrict__ d_w, _Float16* __restrict__ Wh)
{
    const int bid = blockIdx.x, tid = threadIdx.x;
    const int idx = (bid * 256 + tid) * 4;
    const int row = idx >> 8, col = idx & 255;
    const float* src = (row < 32) ? (b_w + row * CCH + col)
                     : (row < 64) ? (c_w + (row - 32) * CCH + col)
                                  : (d_w + (row - 64) * CCH + col);
    const float scl = (row < 32) ? 1.4426950408889634f : 1.0f;
    float4 v = *reinterpret_cast<const float4*>(src);
    _Float16* dst = Wh + (size_t)row * CCH + col;
    dst[0] = (_Float16)(v.x * scl); dst[1] = (_Float16)(v.y * scl);
    dst[2] = (_Float16)(v.z * scl); dst[3] = (_Float16)(v.w * scl);
}

// ---------------------------------------------------------------------------
// Projection kernel v3: COALESCED INPUT LOAD. The old a-load had each thread
// read its own channel row (64 lanes at 16 KB stride = 64 txns/instr) --
// unchanged since round 0 and the prime suspect for proj's hidden cost.
// Now tid -> (ch = pass*32 + tid>>3, seg = tid&7): 8 lanes cover one row's
// 128 B contiguous (2x64B txns per row, 16 txns/instr, 4x better), 8
// independent passes hide latency. LDS transpose target aT[pos][ch],
// MFMA loop and R10 coalesced epilogue unchanged.
// ---------------------------------------------------------------------------
__global__ __launch_bounds__(256) void proj_kernel(
    const float* __restrict__ a, const _Float16* __restrict__ Wh,
    const float* __restrict__ b_b, const float* __restrict__ c_b,
    const float* __restrict__ d_b,
    _Float16* __restrict__ bqT, _Float16* __restrict__ ckT,
    _Float16* __restrict__ dv)
{
    __shared__ _Float16 aT[32][CCH + 24];   // [pos][ch] input transpose
    __shared__ _Float16 oT[256][34];        // dv staging [ch][pos]
    __shared__ _Float16 pqT[32][34];        // bq staging [pos][ch]
    __shared__ _Float16 pkT[32][34];        // ck staging [pos][ch]

    const int n    = blockIdx.x >> 7;
    const int i0   = (blockIdx.x & 127) << 5;
    const int tid  = threadIdx.x;
    const int lane = tid & 63;
    const int wave = tid >> 6;
    const int l15  = lane & 15;
    const int quad = lane >> 4;

    // ---- coalesced a-load: 8 passes x (32 ch x 8 seg); each row's 32 floats
    //      covered by 8 consecutive lanes (128 B contiguous).
    {
        const int ch8 = tid >> 3;           // 0..31: channel within pass
        const int sl8 = tid & 7;            // 16 B segment within row
        #pragma unroll
        for (int pass = 0; pass < 8; ++pass) {
            const int ch = pass*32 + ch8;
            float4 v = *reinterpret_cast<const float4*>(
                a + (size_t)(n*CCH + ch)*NHW + i0 + sl8*4);
            aT[sl8*4+0][ch] = (_Float16)v.x;
            aT[sl8*4+1][ch] = (_Float16)v.y;
            aT[sl8*4+2][ch] = (_Float16)v.z;
            aT[sl8*4+3][ch] = (_Float16)v.w;
        }
    }
    __syncthreads();

    const f32x4 zf = {0.f, 0.f, 0.f, 0.f};
    f32x4 acc[5][2];
    #pragma unroll
    for (int t = 0; t < 5; ++t) { acc[t][0] = zf; acc[t][1] = zf; }

    const int ch0w = wave * 80;

    #pragma unroll
    for (int ks = 0; ks < 8; ++ks) {
        const int k0 = ks * 32;
        hv8 af0 = *reinterpret_cast<const hv8*>(&aT[l15][k0 + quad*8]);
        hv8 af1 = *reinterpret_cast<const hv8*>(&aT[16 + l15][k0 + quad*8]);
        #pragma unroll
        for (int t = 0; t < 5; ++t) {
            const int ch0 = ch0w + t*16;
            hv8 bf = *reinterpret_cast<const hv8*>(
                Wh + (size_t)(ch0 + l15)*CCH + k0 + quad*8);
            acc[t][0] = __builtin_amdgcn_mfma_f32_16x16x32_f16(af0, bf, acc[t][0], 0, 0, 0);
            acc[t][1] = __builtin_amdgcn_mfma_f32_16x16x32_f16(af1, bf, acc[t][1], 0, 0, 0);
        }
    }

    // ---- stage results into LDS (biases applied here)
    const int posq = quad*4;                // local pos base
    #pragma unroll
    for (int t = 0; t < 5; ++t) {
        const int ch0 = ch0w + t*16;
        if (ch0 < 64) {
            const float* bias_arr = (ch0 < 32) ? b_b : c_b;
            const int    ch       = (ch0 & 31) + l15;
            const float  bias     = bias_arr[ch] *
                ((ch0 < 32) ? 1.4426950408889634f : 1.0f);
            #pragma unroll
            for (int nf = 0; nf < 2; ++nf) {
                #pragma unroll
                for (int r = 0; r < 4; ++r) {
                    const int pos = posq + nf*16 + r;
                    if (ch0 < 32) pqT[pos][ch] = (_Float16)(acc[t][nf][r] + bias);
                    else          pkT[pos][ch] = (_Float16)(acc[t][nf][r] + bias);
                }
            }
        } else {
            const int ch   = ch0 - 64 + l15;
            const float bias = d_b[ch];
            #pragma unroll
            for (int nf = 0; nf < 2; ++nf) {
                hv4 v = { (_Float16)(acc[t][nf][0] + bias),
                          (_Float16)(acc[t][nf][1] + bias),
                          (_Float16)(acc[t][nf][2] + bias),
                          (_Float16)(acc[t][nf][3] + bias) };
                *reinterpret_cast<hv4*>(&oT[ch][posq + nf*16]) = v;
            }
        }
    }
    __syncthreads();

    // ---- coalesced global writes
    {
        const int p   = (tid & 127) >> 2;
        const int seg = (tid & 3) << 3;
        if (tid < 128) {
            *reinterpret_cast<int4*>(
                bqT + ((size_t)n*NHW + i0 + p)*CQK + seg) =
                *reinterpret_cast<const int4*>(&pqT[p][seg]);
        } else {
            *reinterpret_cast<int4*>(
                ckT + ((size_t)n*NHW + i0 + p)*CQK + seg) =
                *reinterpret_cast<const int4*>(&pkT[p][seg]);
        }
    }
    #pragma unroll
    for (int pass = 0; pass < 4; ++pass) {
        const int row = pass*64 + (tid >> 2);
        const int seg = (tid & 3) << 3;
        *reinterpret_cast<int4*>(
            dv + ((size_t)(n*CCH + row))*NHW + i0 + seg) =
            *reinterpret_cast<const int4*>(&oT[row][seg]);
    }
}

// ---------------------------------------------------------------------------
// Pass B (R15 VERBATIM, verified best: ~74us): wave-autonomous, zero in-loop
// barriers, single-buffer V via gll16 DMA, T5 setprio around PV MFMA.
// Block = 4 waves = 4 k-groups (1024 keys each), 64q x 128co, KT=32.
// Grid 512, XCD-swizzled. Batched per-group row-max prologue, fixed minit
// softmax, P via pb, 4-way max-align + O/l merge (out of loop).
// smem carve (72704 B): vbuf g*8192 | pb 32768+g*5120 | merge buf1@0,
// buf2@35840 | lbuf@70656 | mbuf@71680.
// ---------------------------------------------------------------------------
__global__ __launch_bounds__(256, 2) void attn_kernel(
    const _Float16* __restrict__ bqT, const _Float16* __restrict__ ckT,
    const _Float16* __restrict__ dv,
    const float* __restrict__ a, const float* __restrict__ alpha_p,
    float* __restrict__ out)
{
    __shared__ __align__(16) char smem[72704];

    // XCD swizzle: 512 blocks, 8 XCDs -> XCD k owns logical [k*64,(k+1)*64)
    const int bx   = ((blockIdx.x & 7) << 6) | (blockIdx.x >> 3);
    const int n    = bx >> 7;
    const int cg   = (bx >> 6) & 1;
    const int qt   = bx & 63;
    const int q0b  = qt << 6;           // block covers 64 q
    const int co0  = cg << 7;           // 128 output channels
    const int tid  = threadIdx.x;
    const int g    = tid >> 6;          // wave = k-group 0..3
    const int lane = tid & 63;
    const int l15  = lane & 15;
    const int quad = lane >> 4;
    const int kg0  = g << 10;           // keys [g*1024, (g+1)*1024)

    _Float16* vbuf = (_Float16*)(smem + g*8192);          // [128 co][32 k] swizzled
    _Float16* pb   = (_Float16*)(smem + 32768 + g*5120);  // 4 slabs of [16][40]
    float*    lbuf = (float*)(smem + 70656);              // [4 g][64 q]
    float*    mbuf = (float*)(smem + 71680);              // [4 g][64 q]

    const f32x4 zf = {0.f, 0.f, 0.f, 0.f};
    const _Float16 one_h = (_Float16)1.0f;
    const hv8 ones = { one_h, one_h, one_h, one_h, one_h, one_h, one_h, one_h };

    // q fragments, 4 groups of 16 q (covers the block's 64 q)
    hv8 qf[4];
    #pragma unroll
    for (int X = 0; X < 4; ++X) {
        const int q = q0b + X*16 + l15;
        qf[X] = *reinterpret_cast<const hv8*>(
            bqT + ((size_t)n*NHW + q)*CQK + quad*8);
    }

    // kf base for this lane within this group's key range
    const _Float16* ckbase = ckT + ((size_t)(n*NHW + kg0 + l15))*CQK + quad*8;

    // ---- batched per-group row-max prologue: 8 batches x 8 kf (1024 keys)
    float mneg[4];
    {
        float mx[4] = {-1e30f, -1e30f, -1e30f, -1e30f};
        #pragma unroll
        for (int bt = 0; bt < 8; ++bt) {
            hv8 kb[8];
            #pragma unroll
            for (int j = 0; j < 8; ++j)
                kb[j] = *reinterpret_cast<const hv8*>(
                    ckbase + (size_t)(bt*128 + j*16)*CQK);
            #pragma unroll
            for (int X = 0; X < 4; ++X) {
                float bm[8];
                #pragma unroll
                for (int j = 0; j < 8; ++j) {
                    f32x4 s = __builtin_amdgcn_mfma_f32_16x16x32_f16(
                        kb[j], qf[X], zf, 0, 0, 0);
                    bm[j] = fmaxf(fmaxf(s[0], s[1]), fmaxf(s[2], s[3]));
                }
                float m0 = fmaxf(fmaxf(bm[0], bm[1]), fmaxf(bm[2], bm[3]));
                float m1 = fmaxf(fmaxf(bm[4], bm[5]), fmaxf(bm[6], bm[7]));
                mx[X] = fmaxf(mx[X], fmaxf(m0, m1));
            }
        }
        #pragma unroll
        for (int X = 0; X < 4; ++X) {
            mx[X] = fmaxf(mx[X], __shfl_xor(mx[X], 16, 64));
            mx[X] = fmaxf(mx[X], __shfl_xor(mx[X], 32, 64));
            mneg[X] = -mx[X];
        }
    }

    f32x4 acc[4][8];
    #pragma unroll
    for (int X = 0; X < 4; ++X)
        #pragma unroll
        for (int t = 0; t < 8; ++t) acc[X][t] = zf;
    f32x4 accL[4];
    #pragma unroll
    for (int X = 0; X < 4; ++X) accL[X] = zf;

    // ---- staging: 8 x gll16 per wave covers 128 co rows x 32 k.
    const int rl4 = lane >> 2;
    const int sl  = lane & 3;
    const _Float16* dvs = dv
        + (size_t)(n*CCH + co0 + rl4)*NHW + kg0 + 8*(sl ^ ((rl4 >> 1) & 3));

    // swizzled V read col (halves): k-slot quad*8 XOR row-hash
    const int c0h = (quad*8) ^ (((l15 >> 1) & 3) << 3);

    // S^T/exp for one 32-key tile, all 4 q-groups -> pb (fixed minit)
    auto softmax_tile = [&](const hv8* kf) {
        #pragma unroll
        for (int X = 0; X < 4; ++X) {
            const f32x4 minit = {mneg[X], mneg[X], mneg[X], mneg[X]};
            #pragma unroll
            for (int f = 0; f < 2; ++f) {
                f32x4 s = __builtin_amdgcn_mfma_f32_16x16x32_f16(
                    kf[f], qf[X], minit, 0, 0, 0);
                float p0 = __builtin_amdgcn_exp2f(s[0]);
                float p1 = __builtin_amdgcn_exp2f(s[1]);
                float p2 = __builtin_amdgcn_exp2f(s[2]);
                float p3 = __builtin_amdgcn_exp2f(s[3]);
                fv2 lo = __builtin_amdgcn_cvt_pkrtz(p0, p1);
                fv2 hi = __builtin_amdgcn_cvt_pkrtz(p2, p3);
                uint2 w;
                w.x = __builtin_bit_cast(unsigned, lo);
                w.y = __builtin_bit_cast(unsigned, hi);
                *reinterpret_cast<uint2*>(
                    pb + X*640 + l15*40 + f*16 + quad*4) = w;
            }
        }
    };

    hv8 pf0[4];
    auto read_pf = [&]() {
        #pragma unroll
        for (int X = 0; X < 4; ++X)
            pf0[X] = *reinterpret_cast<const hv8*>(pb + X*640 + l15*40 + quad*8);
    };

    auto stage = [&](int kt) {
        #pragma unroll
        for (int j = 0; j < 8; ++j)
            gll16(dvs + (size_t)(j*16)*NHW + kt*32, vbuf + j*512);
    };

    auto load_kf = [&](int key0, hv8* kf) {
        #pragma unroll
        for (int f = 0; f < 2; ++f)
            kf[f] = *reinterpret_cast<const hv8*>(
                ckbase + (size_t)(key0 + f*16)*CQK);
    };

    // ---- prologue: stage V(0), softmax(0) under the DMA, wait, pf(0)
    {
        stage(0);
        hv8 kf0[2];
        load_kf(0, kf0);
        softmax_tile(kf0);
        read_pf();
        asm volatile("s_waitcnt vmcnt(0)" ::: "memory");
        __builtin_amdgcn_sched_barrier(0);
    }

    for (int kt = 0; kt < 32; ++kt) {
        hv8 kfn[2];
        if (kt < 31) load_kf((kt + 1)*32, kfn);

        // ---- PV(kt): each V fragment feeds 4 q-groups (T5 setprio wrap)
        __builtin_amdgcn_s_setprio(1);
        #pragma unroll
        for (int t = 0; t < 8; ++t) {
            hv8 d0 = *reinterpret_cast<const hv8*>(vbuf + (t*16 + l15)*32 + c0h);
            #pragma unroll
            for (int X = 0; X < 4; ++X)
                acc[X][t] = __builtin_amdgcn_mfma_f32_16x16x32_f16(
                    pf0[X], d0, acc[X][t], 0, 0, 0);
        }
        #pragma unroll
        for (int X = 0; X < 4; ++X)
            accL[X] = __builtin_amdgcn_mfma_f32_16x16x32_f16(pf0[X], ones, accL[X], 0, 0, 0);
        __builtin_amdgcn_s_setprio(0);

        if (kt < 31) {
            // all V(kt) ds_reads retired -> buffer reusable (same wave only)
            asm volatile("s_waitcnt lgkmcnt(0)" ::: "memory");
            __builtin_amdgcn_sched_barrier(0);
            stage(kt + 1);              // DMA issue
            softmax_tile(kfn);          // covers DMA latency (MFMA+exp+pb)
            read_pf();                  // pf(kt+1), same-wave LDS order
            asm volatile("s_waitcnt vmcnt(0)" ::: "memory");   // DMA landed
            __builtin_amdgcn_sched_barrier(0);
        }
    }

    // ---- align k-group partials to common max, merge, epilogue
    if (lane < 16) {
        #pragma unroll
        for (int X = 0; X < 4; ++X)
            mbuf[g*64 + X*16 + l15] = -mneg[X];
    }
    __syncthreads();

    {
        #pragma unroll
        for (int X = 0; X < 4; ++X) {
            const int qloc = X*16 + quad*4;
            float4 m0 = *reinterpret_cast<float4*>(&mbuf[0*64 + qloc]);
            float4 m1 = *reinterpret_cast<float4*>(&mbuf[1*64 + qloc]);
            float4 m2 = *reinterpret_cast<float4*>(&mbuf[2*64 + qloc]);
            float4 m3 = *reinterpret_cast<float4*>(&mbuf[3*64 + qloc]);
            float4 mm;
            mm.x = fmaxf(fmaxf(m0.x, m1.x), fmaxf(m2.x, m3.x));
            mm.y = fmaxf(fmaxf(m0.y, m1.y), fmaxf(m2.y, m3.y));
            mm.z = fmaxf(fmaxf(m0.z, m1.z), fmaxf(m2.z, m3.z));
            mm.w = fmaxf(fmaxf(m0.w, m1.w), fmaxf(m2.w, m3.w));
            float4 mo = (g == 0) ? m0 : (g == 1) ? m1 : (g == 2) ? m2 : m3;
            float sc0 = __builtin_amdgcn_exp2f(mo.x - mm.x);
            float sc1 = __builtin_amdgcn_exp2f(mo.y - mm.y);
            float sc2 = __builtin_amdgcn_exp2f(mo.z - mm.z);
            float sc3 = __builtin_amdgcn_exp2f(mo.w - mm.w);
            #pragma unroll
            for (int t = 0; t < 8; ++t) {
                acc[X][t][0] *= sc0; acc[X][t][1] *= sc1;
                acc[X][t][2] *= sc2; acc[X][t][3] *= sc3;
            }
            accL[X][0] *= sc0; accL[X][1] *= sc1;
            accL[X][2] *= sc2; accL[X][3] *= sc3;
        }
    }
    if (l15 == 0) {
        #pragma unroll
        for (int X = 0; X < 4; ++X)
            *reinterpret_cast<float4*>(&lbuf[g*64 + X*16 + quad*4]) =
                *reinterpret_cast<float4*>(&accL[X]);
    }
    __syncthreads();

    float* buf1 = (float*)smem;                   // [128 co][68 q]
    float* buf2 = (float*)(smem + 35840);

    // Round A: g1 -> buf1, g3 -> buf2
    if (g == 1 || g == 3) {
        float* b = (g == 1) ? buf1 : buf2;
        #pragma unroll
        for (int X = 0; X < 4; ++X)
            #pragma unroll
            for (int t = 0; t < 8; ++t)
                *reinterpret_cast<float4*>(
                    &b[(t*16 + l15)*68 + X*16 + quad*4]) =
                    *reinterpret_cast<float4*>(&acc[X][t]);
    }
    __syncthreads();
    if (g == 0 || g == 2) {
        float* b = (g == 0) ? buf1 : buf2;
        #pragma unroll
        for (int X = 0; X < 4; ++X)
            #pragma unroll
            for (int t = 0; t < 8; ++t) {
                float4 p = *reinterpret_cast<float4*>(
                    &b[(t*16 + l15)*68 + X*16 + quad*4]);
                acc[X][t][0] += p.x; acc[X][t][1] += p.y;
                acc[X][t][2] += p.z; acc[X][t][3] += p.w;
            }
    }
    __syncthreads();
    // Round B: g2 -> buf1
    if (g == 2) {
        #pragma unroll
        for (int X = 0; X < 4; ++X)
            #pragma unroll
            for (int t = 0; t < 8; ++t)
                *reinterpret_cast<float4*>(
                    &buf1[(t*16 + l15)*68 + X*16 + quad*4]) =
                    *reinterpret_cast<float4*>(&acc[X][t]);
    }
    __syncthreads();
    if (g == 0) {
        const float alpha = alpha_p[0];
        #pragma unroll
        for (int X = 0; X < 4; ++X) {
            const int qloc = X*16 + quad*4;
            #pragma unroll
            for (int t = 0; t < 8; ++t) {
                float4 p = *reinterpret_cast<float4*>(
                    &buf1[(t*16 + l15)*68 + qloc]);
                acc[X][t][0] += p.x; acc[X][t][1] += p.y;
                acc[X][t][2] += p.z; acc[X][t][3] += p.w;
            }
            float4 l0 = *reinterpret_cast<float4*>(&lbuf[0*64 + qloc]);
            float4 l1 = *reinterpret_cast<float4*>(&lbuf[1*64 + qloc]);
            float4 l2 = *reinterpret_cast<float4*>(&lbuf[2*64 + qloc]);
            float4 l3 = *reinterpret_cast<float4*>(&lbuf[3*64 + qloc]);
            f32x4 rl;
            rl[0] = alpha / (l0.x + l1.x + l2.x + l3.x);
            rl[1] = alpha / (l0.y + l1.y + l2.y + l3.y);
            rl[2] = alpha / (l0.z + l1.z + l2.z + l3.z);
            rl[3] = alpha / (l0.w + l1.w + l2.w + l3.w);
            #pragma unroll
            for (int t = 0; t < 8; ++t) {
                const size_t off =
                    ((size_t)(n*CCH + co0 + t*16 + l15))*NHW + q0b + qloc;
                float4 av = *reinterpret_cast<const float4*>(a + off);
                float4 o;
                o.x = acc[X][t][0]*rl[0] + av.x;
                o.y = acc[X][t][1]*rl[1] + av.y;
                o.z = acc[X][t][2]*rl[2] + av.z;
                o.w = acc[X][t][3]*rl[3] + av.w;
                *reinterpret_cast<float4*>(out + off) = o;
            }
        }
    }
}

extern "C" void kernel_launch(void* const* d_in, const int* in_sizes, int n_in,
                              void* d_out, int out_size, void* d_ws, size_t ws_size,
                              hipStream_t stream)
{
    const float* a    = (const float*)d_in[0];
    const float* b_w  = (const float*)d_in[1];
    const float* b_b  = (const float*)d_in[2];
    const float* c_w  = (const float*)d_in[3];
    const float* c_b  = (const float*)d_in[4];
    const float* d_w  = (const float*)d_in[5];
    const float* d_b  = (const float*)d_in[6];
    const float* alp  = (const float*)d_in[7];
    float* out = (float*)d_out;

    _Float16* bqT  = (_Float16*)d_ws;                 // [4][4096][32] fp16, 1 MB
    _Float16* ckT  = bqT + (size_t)4*NHW*CQK;         // [4][4096][32] fp16, 1 MB
    _Float16* dv   = ckT + (size_t)4*NHW*CQK;         // [4][256][4096] fp16, 8 MB
    _Float16* Wh   = dv + (size_t)4*CCH*NHW;          // [320][256] fp16, 160 KB

    prep_kernel<<<80, 256, 0, stream>>>(b_w, c_w, d_w, Wh);
    proj_kernel<<<512, 256, 0, stream>>>(a, Wh, b_b, c_b, d_b, bqT, ckT, dv);
    attn_kernel<<<512, 256, 0, stream>>>(bqT, ckT, dv, a, alp, out);
}